// Round 14
// baseline (721.034 us; speedup 1.0000x reference)
//
#include <hip/hip_runtime.h>
#include <math.h>

#define ACT_LRELU  0
#define ACT_SIGMAP 1
#define ACT_SQUARE 2

typedef __attribute__((ext_vector_type(8))) short v8s;
typedef __attribute__((ext_vector_type(4))) short v4s;
typedef __attribute__((ext_vector_type(16))) float f32x16;

static __device__ __forceinline__ float lrelu(float x) { return x >= 0.f ? x : 0.2f * x; }

static __device__ __forceinline__ short bf16rne(float x) {
  unsigned u = __float_as_uint(x);
  unsigned r = (u + 0x7FFFu + ((u >> 16) & 1u)) >> 16;
  return (short)r;
}
static __device__ __forceinline__ float bf16tof(short h) {
  return __uint_as_float(((unsigned)(unsigned short)h) << 16);
}
static __device__ __forceinline__ void split3(float v, short& h, short& l, short& q) {
  h = bf16rne(v); float r1 = v - bf16tof(h);
  l = bf16rne(r1); float r2 = r1 - bf16tof(l);
  q = bf16rne(r2);
}

// ---------------- shared-memory layouts ----------------
struct SMPathT {
  short Al[3][64 * 72];
  short Bl[3][64 * 72];
  float bandS[2][128];
};
template<int BM, int SLAB>
struct SMNoiseT {
  short Al[2][BM * 72];
  short Bl[2][SLAB * 72];
};
template<int BM, int SLAB>
union SMFusedU {
  SMPathT p;
  SMNoiseT<BM, SLAB> n;
};

// -------------------------------------------------------------------------
// prep_all: block-range dispatch.
//  [0,512)      prep_acts:   x -> xm3 3-plane bf16 [pl][b][t][ci]
//  [512,1408)   prep_panels: m/g weights -> 3-plane tap-major panels
//  [1408,1832)  fold: noise weights -> folded parity hi/lo panels + Pnl
// Serial schedule launches only 1408 blocks (fold range deferred — its
// outputs alias live phase-A memory there). Overlapped schedule (disjoint
// layout) launches 1832.
// -------------------------------------------------------------------------
__global__ void __launch_bounds__(256) prep_all(
    const float* __restrict__ x, short* __restrict__ xm3,
    const float* mw0, const float* mw1, const float* mw2, const float* mw3, const float* fw,
    const float* gw0, const float* gw1, const float* gw2, const float* gw3, const float* lw,
    short* __restrict__ mP, short* __restrict__ gP,
    const float* __restrict__ nw0, const float* __restrict__ nw1,
    const float* __restrict__ nw2, const float* __restrict__ nw3,
    const float* __restrict__ nlw,
    short* __restrict__ E1, short* __restrict__ E2,
    short* __restrict__ E3, short* __restrict__ E4,
    short* __restrict__ Pnl)
{
  const int blk = blockIdx.x;
  const int tid = threadIdx.x;

  if (blk < 512) {
    int e = blk * 256 + tid;
    if (e >= 131072) return;
    int b = e >> 13, rem = e & 8191, t = rem >> 7, ci = rem & 127;
    float v = x[((size_t)(b * 128) + ci) * 64 + t];
    short h, l, q; split3(v, h, l, q);
    size_t o = ((size_t)(b * 64) + t) * 128 + ci;
    xm3[0 * 131072 + o] = h;
    xm3[1 * 131072 + o] = l;
    xm3[2 * 131072 + o] = q;
    return;
  }

  if (blk < 1408) {
    int i = (blk - 512) * 256 + tid;
    const int PER = 114688;
    if (i >= 2 * PER) return;
    int path = i >= PER ? 1 : 0;
    int r = i - path * PER;
    int Cin, Cout; size_t poff;
    const float* W;
    {
      int layer;
      if (r < 8192)        { layer = 0;              Cin = 128; Cout = 512; poff = 0; }
      else if (r < 40960)  { layer = 1; r -= 8192;   Cin = 512; Cout = 512; poff = 589824; }
      else if (r < 73728)  { layer = 2; r -= 40960;  Cin = 512; Cout = 512; poff = 2949120; }
      else if (r < 106496) { layer = 3; r -= 73728;  Cin = 512; Cout = 512; poff = 5308416; }
      else                 { layer = 4; r -= 106496; Cin = 512; Cout = 128; poff = 7667712; }
      const float* Wm[5] = {mw0, mw1, mw2, mw3, fw};
      const float* Wg[5] = {gw0, gw1, gw2, gw3, lw};
      W = path ? Wg[layer] : Wm[layer];
    }
    short* P = (path ? gP : mP) + poff;
    const int nci8 = Cin >> 3;
    int co = r / nci8, ci = (r - co * nci8) * 8;
    const int K3 = 3 * Cin;
    const float* wp = W + (size_t)(co * Cin + ci) * 3;
    v8s hv[3], lv[3], qv[3];
#pragma unroll
    for (int j = 0; j < 8; ++j)
#pragma unroll
      for (int tap = 0; tap < 3; ++tap) {
        short h, l, q; split3(wp[j * 3 + tap], h, l, q);
        hv[tap][j] = h; lv[tap][j] = l; qv[tap][j] = q;
      }
#pragma unroll
    for (int tap = 0; tap < 3; ++tap) {
      size_t base = (size_t)co * K3 + tap * Cin + ci;
      *(v8s*)&P[(size_t)0 * Cout * K3 + base] = hv[tap];
      *(v8s*)&P[(size_t)1 * Cout * K3 + base] = lv[tap];
      *(v8s*)&P[(size_t)2 * Cout * K3 + base] = qv[tap];
    }
    return;
  }

  // ---- fold range ----
  int i = (blk - 1408) * 256 + tid;
  if (i >= 106496) {
    if (i >= 108544) return;
    int idx = i - 106496;
    int co = idx >> 6, ci = (idx & 63) * 8;
    v8s hv[3], lv[3];
#pragma unroll
    for (int j = 0; j < 8; ++j)
#pragma unroll
      for (int tap = 0; tap < 3; ++tap) {
        float v = (co < 17) ? nlw[((size_t)(co * 512 + ci + j)) * 3 + tap] : 0.f;
        short h = bf16rne(v);
        hv[tap][j] = h;
        lv[tap][j] = bf16rne(v - bf16tof(h));
      }
#pragma unroll
    for (int tap = 0; tap < 3; ++tap) {
      *(v8s*)&Pnl[(size_t)(0 * 32 + co) * 1536 + tap * 512 + ci] = hv[tap];
      *(v8s*)&Pnl[(size_t)(1 * 32 + co) * 1536 + tap * 512 + ci] = lv[tap];
    }
    return;
  }
  const float* W; short* Ag; int Cin; int idx;
  if (i < 8192)        { W = nw0; Ag = E1; Cin = 128; idx = i; }
  else if (i < 40960)  { W = nw1; Ag = E2; Cin = 512; idx = i - 8192; }
  else if (i < 73728)  { W = nw2; Ag = E3; Cin = 512; idx = i - 40960; }
  else                 { W = nw3; Ag = E4; Cin = 512; idx = i - 73728; }
  const int nci8 = Cin >> 3;
  int co = idx / nci8, ci = (idx - co * nci8) * 8;
  const float* wp = W + (size_t)(co * Cin + ci) * 7;
  const int K = Cin * 4;
  v8s he[4], le[4], ho[4], lo4[4];
#pragma unroll
  for (int j = 0; j < 8; ++j) {
    const float* w = wp + j * 7;
    float fe[4] = {w[0],        w[1] + w[2], w[3] + w[4], w[5] + w[6]};
    float fo[4] = {w[0] + w[1], w[2] + w[3], w[4] + w[5], w[6]};
#pragma unroll
    for (int q = 0; q < 4; ++q) {
      short h1 = bf16rne(fe[q]);
      he[q][j] = h1; le[q][j] = bf16rne(fe[q] - bf16tof(h1));
      short h2 = bf16rne(fo[q]);
      ho[q][j] = h2; lo4[q][j] = bf16rne(fo[q] - bf16tof(h2));
    }
  }
#pragma unroll
  for (int q = 0; q < 4; ++q) {
    size_t kbase = (size_t)q * Cin + ci;
    *(v8s*)&Ag[((size_t)(0 * 512 + co)) * K + kbase] = he[q];
    *(v8s*)&Ag[((size_t)(1 * 512 + co)) * K + kbase] = le[q];
    *(v8s*)&Ag[((size_t)(2 * 512 + co)) * K + kbase] = ho[q];
    *(v8s*)&Ag[((size_t)(3 * 512 + co)) * K + kbase] = lo4[q];
  }
}

// -------------------------------------------------------------------------
// m/g path conv body: 3-plane split-bf16 MFMA GEMM, 32x32x16, T14 staging.
// -------------------------------------------------------------------------
__device__ __forceinline__ void conv_path_body(
    SMPathT& sm, int bidx,
    const short* __restrict__ actM, const short* __restrict__ actG,
    const short* __restrict__ Pm, const short* __restrict__ Pg,
    const float* __restrict__ BsM, const float* __restrict__ BsG,
    float* __restrict__ foutM, float* __restrict__ foutG,
    short* __restrict__ soutM, short* __restrict__ soutG,
    int Cin, int Cout, int psIn, int psOut, int actMk, int actGk)
{
  const int mtiles = Cout >> 6;
  const int nblk = 2 * mtiles * 16;
  const int Q = nblk >> 3;
  int d = bidx;
  int idx = (d & 7) * Q + (d >> 3);
  int mt = idx % mtiles;
  int tmp = idx / mtiles;
  int nt = tmp & 15;
  int path = tmp >> 4;

  const short* act = path ? actG : actM;
  const short* P   = path ? Pg : Pm;
  const float* Bs  = path ? BsG : BsM;
  float* fout      = path ? foutG : foutM;
  short* sout      = path ? soutG : soutM;
  const int actk   = path ? actGk : actMk;

  const int K3 = 3 * Cin;
  const int co0 = mt * 64;
  const int n0  = nt * 64;
  const int nci = Cin >> 6;
  const int NT  = 3 * nci;

  const int tid = threadIdx.x;
  const int w = tid >> 6, wm = w & 1, wn = w >> 1;
  const int l = tid & 63;

  if (actk == ACT_SIGMAP && tid < 128) {
    double lg = log(551.25);
    double stop  = 20.0 * exp(lg * (double)tid / 127.0);
    double start = (tid == 0) ? 0.0 : 20.0 * exp(lg * (double)(tid - 1) / 127.0);
    sm.bandS[0][tid] = (float)start;
    sm.bandS[1][tid] = (float)(stop - start);
  }

  f32x16 acc = {};
  v8s rA[3][2], rB[3][2];

  auto LOADA = [&](int t) {
    int tap = t / nci, ci0 = (t % nci) << 6;
#pragma unroll
    for (int pl = 0; pl < 3; ++pl)
#pragma unroll
      for (int it = 0; it < 2; ++it) {
        int e = it * 256 + tid;
        int row = e >> 3, c8 = e & 7;
        rA[pl][it] = *(const v8s*)&P[(size_t)pl * Cout * K3 + (size_t)(co0 + row) * K3
                                     + tap * Cin + ci0 + c8 * 8];
      }
  };
  auto LOADB = [&](int t) {
    int tap = t / nci, ci0 = (t % nci) << 6;
#pragma unroll
    for (int pl = 0; pl < 3; ++pl)
#pragma unroll
      for (int it = 0; it < 2; ++it) {
        int e = it * 256 + tid;
        int n = e >> 3, c8 = e & 7;
        int gn = n0 + n, bb = gn >> 6, trow = (gn & 63) + tap - 1;
        v8s vv = {};
        if (trow >= 0 && trow < 64)
          vv = *(const v8s*)&act[(size_t)pl * psIn + ((size_t)(bb * 64 + trow)) * Cin
                                 + ci0 + c8 * 8];
        rB[pl][it] = vv;
      }
  };
  auto WRITE = [&]() {
#pragma unroll
    for (int pl = 0; pl < 3; ++pl)
#pragma unroll
      for (int it = 0; it < 2; ++it) {
        int e = it * 256 + tid;
        int row = e >> 3, c8 = e & 7;
        *(v8s*)&sm.Al[pl][row * 72 + c8 * 8] = rA[pl][it];
        *(v8s*)&sm.Bl[pl][row * 72 + c8 * 8] = rB[pl][it];
      }
  };

  LOADA(0); LOADB(0);
  WRITE();
  __syncthreads();

  for (int t = 0; t < NT; ++t) {
    if (t + 1 < NT) { LOADA(t + 1); LOADB(t + 1); }
    const int abase = (wm * 32 + (l & 31)) * 72 + (l >> 5) * 8;
    const int bbase = (wn * 32 + (l & 31)) * 72 + (l >> 5) * 8;
#pragma unroll
    for (int kk = 0; kk < 4; ++kk) {
      v8s a0 = *(const v8s*)&sm.Al[0][abase + kk * 16];
      v8s a1 = *(const v8s*)&sm.Al[1][abase + kk * 16];
      v8s a2 = *(const v8s*)&sm.Al[2][abase + kk * 16];
      v8s b0 = *(const v8s*)&sm.Bl[0][bbase + kk * 16];
      v8s b1 = *(const v8s*)&sm.Bl[1][bbase + kk * 16];
      v8s b2 = *(const v8s*)&sm.Bl[2][bbase + kk * 16];
      acc = __builtin_amdgcn_mfma_f32_32x32x16_bf16(a0, b0, acc, 0, 0, 0);
      acc = __builtin_amdgcn_mfma_f32_32x32x16_bf16(a0, b1, acc, 0, 0, 0);
      acc = __builtin_amdgcn_mfma_f32_32x32x16_bf16(a1, b0, acc, 0, 0, 0);
      acc = __builtin_amdgcn_mfma_f32_32x32x16_bf16(a1, b1, acc, 0, 0, 0);
      acc = __builtin_amdgcn_mfma_f32_32x32x16_bf16(a0, b2, acc, 0, 0, 0);
      acc = __builtin_amdgcn_mfma_f32_32x32x16_bf16(a2, b0, acc, 0, 0, 0);
    }
    __syncthreads();
    if (t + 1 < NT) { WRITE(); __syncthreads(); }
  }

  const int ncol = wn * 32 + (l & 31);
  const int gn = n0 + ncol, bb = gn >> 6, t = gn & 63;
  const int hi4 = 4 * (l >> 5);
#pragma unroll
  for (int q4 = 0; q4 < 4; ++q4) {
    int co = co0 + wm * 32 + q4 * 8 + hi4;
    float4 bia = *(const float4*)&Bs[co];
    const float* bp = &bia.x;
    float z[4];
#pragma unroll
    for (int j = 0; j < 4; ++j) z[j] = acc[q4 * 4 + j] + bp[j];
    if (actk == ACT_LRELU) {
      v4s h4, l4, q4v;
#pragma unroll
      for (int j = 0; j < 4; ++j) {
        float zz = lrelu(z[j]);
        short h, lo, qq; split3(zz, h, lo, qq);
        h4[j] = h; l4[j] = lo; q4v[j] = qq;
      }
      size_t o = ((size_t)(bb * 64) + t) * Cout + co;
      *(v4s*)&sout[0 * (size_t)psOut + o] = h4;
      *(v4s*)&sout[1 * (size_t)psOut + o] = l4;
      *(v4s*)&sout[2 * (size_t)psOut + o] = q4v;
    } else if (actk == ACT_SIGMAP) {
#pragma unroll
      for (int j = 0; j < 4; ++j) {
        float f = sm.bandS[0][co + j] + sm.bandS[1][co + j] / (1.f + expf(-z[j]));
        fout[((size_t)(bb * 128) + co + j) * 64 + t] = f;
      }
    } else {
#pragma unroll
      for (int j = 0; j < 4; ++j)
        fout[((size_t)(bb * 128) + co + j) * 64 + t] = z[j] * z[j];
    }
  }
}

// -------------------------------------------------------------------------
// Noise conv body: ci-OUTER / q-INNER with shared B-slab.
// -------------------------------------------------------------------------
template<int MF, int BNS, int CIN>
__device__ __forceinline__ void conv_noise_body(
    SMNoiseT<MF * 64, BNS + 3>& sm, int bidx,
    const short* __restrict__ actIn, const short* __restrict__ Ag,
    const float* __restrict__ Bs, short* __restrict__ actOut,
    int Sin, int psIn, int psOut)
{
  constexpr int NF   = BNS / 64;
  constexpr int BM   = MF * 64;
  constexpr int AITS = BM / 32;
  constexpr int SLAB = BNS + 3;
  constexpr int BSL  = (2 * SLAB * 8 + 255) / 256;
  constexpr int K    = CIN * 4;
  constexpr int nci  = CIN / 64;
  const int mtiles = 512 / BM;
  const int stiles = Sin / BNS;
  const int nblk = mtiles * 2 * 16 * stiles;
  const int Q = nblk >> 3;
  int d = bidx;
  int idx = (d & 7) * Q + (d >> 3);
  int mt = idx % mtiles;
  int t1 = idx / mtiles;
  int par = t1 & 1;
  int rest = t1 >> 1;
  int st = rest % stiles;
  int b = rest / stiles;

  const int co0 = mt * BM;
  const int s0 = st * BNS;
  const int soff = par ? -1 : -2;

  const int tid = threadIdx.x;
  const int w = tid >> 6, wm = w & 1, wn = w >> 1;
  const int l = tid & 63;

  f32x16 acc[MF][NF] = {};
  v8s rA[2][AITS];
  v8s rBS[BSL];

  auto LOADA = [&](int q, int ci0) {
#pragma unroll
    for (int pl = 0; pl < 2; ++pl)
#pragma unroll
      for (int it = 0; it < AITS; ++it) {
        int e = it * 256 + tid;
        int row = e >> 3, c8 = e & 7;
        rA[pl][it] = *(const v8s*)&Ag[((size_t)((par * 2 + pl) * 512 + co0 + row)) * K
                                      + q * CIN + ci0 + c8 * 8];
      }
  };
  auto WRITEA = [&]() {
#pragma unroll
    for (int pl = 0; pl < 2; ++pl)
#pragma unroll
      for (int it = 0; it < AITS; ++it) {
        int e = it * 256 + tid;
        *(v8s*)&sm.Al[pl][(e >> 3) * 72 + (e & 7) * 8] = rA[pl][it];
      }
  };
  auto LOADBS = [&](int ci0) {
#pragma unroll
    for (int it = 0; it < BSL; ++it) {
      int e = it * 256 + tid;
      v8s vv = {};
      if (e < 2 * SLAB * 8) {
        int r3 = e >> 3, c8 = e & 7;
        int pl = r3 / SLAB, row = r3 - pl * SLAB;
        int srow = s0 + soff + row;
        if (srow >= 0 && srow < Sin)
          vv = *(const v8s*)&actIn[(size_t)pl * psIn + ((size_t)(b * Sin + srow)) * CIN
                                   + ci0 + c8 * 8];
      }
      rBS[it] = vv;
    }
  };
  auto WRITEBS = [&]() {
#pragma unroll
    for (int it = 0; it < BSL; ++it) {
      int e = it * 256 + tid;
      if (e < 2 * SLAB * 8) {
        int r3 = e >> 3, c8 = e & 7;
        int pl = r3 / SLAB, row = r3 - pl * SLAB;
        *(v8s*)&sm.Bl[pl][row * 72 + c8 * 8] = rBS[it];
      }
    }
  };

  LOADBS(0); LOADA(0, 0);
  WRITEBS(); WRITEA();
  __syncthreads();

  for (int ci = 0; ci < nci; ++ci) {
    const int ci0 = ci << 6;
#pragma unroll
    for (int q = 0; q < 4; ++q) {
      const bool lastq = (q == 3);
      const bool lastall = lastq && (ci == nci - 1);
      if (!lastq)        LOADA(q + 1, ci0);
      else if (!lastall) { LOADBS(ci0 + 64); LOADA(0, ci0 + 64); }

      const int lr = l & 31, lh = (l >> 5) * 8;
#pragma unroll
      for (int kk = 0; kk < 4; ++kk) {
        v8s ah[MF], al[MF], bh[NF], bl[NF];
#pragma unroll
        for (int fm = 0; fm < MF; ++fm) {
          int ab = (wm * (MF * 32) + fm * 32 + lr) * 72 + kk * 16 + lh;
          ah[fm] = *(const v8s*)&sm.Al[0][ab];
          al[fm] = *(const v8s*)&sm.Al[1][ab];
        }
#pragma unroll
        for (int fn = 0; fn < NF; ++fn) {
          int bb = (wn * (BNS / 2) + fn * 32 + lr + q) * 72 + kk * 16 + lh;
          bh[fn] = *(const v8s*)&sm.Bl[0][bb];
          bl[fn] = *(const v8s*)&sm.Bl[1][bb];
        }
#pragma unroll
        for (int fm = 0; fm < MF; ++fm)
#pragma unroll
          for (int fn = 0; fn < NF; ++fn) {
            acc[fm][fn] = __builtin_amdgcn_mfma_f32_32x32x16_bf16(ah[fm], bh[fn], acc[fm][fn], 0, 0, 0);
            acc[fm][fn] = __builtin_amdgcn_mfma_f32_32x32x16_bf16(ah[fm], bl[fn], acc[fm][fn], 0, 0, 0);
            acc[fm][fn] = __builtin_amdgcn_mfma_f32_32x32x16_bf16(al[fm], bh[fn], acc[fm][fn], 0, 0, 0);
          }
      }
      __syncthreads();
      if (!lastall) {
        if (!lastq) WRITEA();
        else { WRITEBS(); WRITEA(); }
        __syncthreads();
      }
    }
  }

  const int hi4 = 4 * (l >> 5);
  const int T2 = 2 * Sin;
#pragma unroll
  for (int fm = 0; fm < MF; ++fm)
#pragma unroll
    for (int q4 = 0; q4 < 4; ++q4) {
      int co = co0 + wm * (MF * 32) + fm * 32 + q4 * 8 + hi4;
      float4 bia = *(const float4*)&Bs[co];
      const float* bp = &bia.x;
#pragma unroll
      for (int fn = 0; fn < NF; ++fn) {
        int s_l = wn * (BNS / 2) + fn * 32 + (l & 31);
        int t = 2 * (s0 + s_l) + par;
        v4s h4, l4;
#pragma unroll
        for (int j = 0; j < 4; ++j) {
          float z = lrelu(acc[fm][fn][q4 * 4 + j] + bp[j]);
          short h = bf16rne(z);
          h4[j] = h;
          l4[j] = bf16rne(z - bf16tof(h));
        }
        size_t o = ((size_t)(b * T2) + t) * 512 + co;
        *(v4s*)&actOut[0 * (size_t)psOut + o] = h4;
        *(v4s*)&actOut[1 * (size_t)psOut + o] = l4;
      }
    }
}

// ---------------- kernel wrappers ----------------
__global__ void __launch_bounds__(256, 2) k_conv_path(
    const short* actM, const short* actG, const short* Pm, const short* Pg,
    const float* BsM, const float* BsG,
    float* foutM, float* foutG, short* soutM, short* soutG,
    int Cin, int Cout, int psIn, int psOut, int actMk, int actGk)
{
  __shared__ SMPathT sm;
  conv_path_body(sm, blockIdx.x, actM, actG, Pm, Pg, BsM, BsG,
                 foutM, foutG, soutM, soutG, Cin, Cout, psIn, psOut, actMk, actGk);
}

template<int MF, int BNS, int CIN>
__global__ void __launch_bounds__(256, 2) k_conv_noise(
    const short* actIn, const short* Ag, const float* Bs, short* actOut,
    int Sin, int psIn, int psOut)
{
  __shared__ SMNoiseT<MF * 64, BNS + 3> sm;
  conv_noise_body<MF, BNS, CIN>(sm, blockIdx.x, actIn, Ag, Bs, actOut, Sin, psIn, psOut);
}

// fused: blocks [0,mgBlocks) run conv_path; the rest run conv_noise.
template<int MF, int BNS, int CIN>
__global__ void __launch_bounds__(256, 2) k_fused(
    const short* actM, const short* actG, const short* Pm, const short* Pg,
    const float* BsM, const float* BsG,
    float* foutM, float* foutG, short* soutM, short* soutG,
    int Cin, int Cout, int psIn, int psOut, int actMk, int actGk,
    const short* nActIn, const short* nAg, const float* nBs, short* nActOut,
    int nSin, int nPsIn, int nPsOut, int mgBlocks)
{
  __shared__ SMFusedU<MF * 64, BNS + 3> sm;
  if ((int)blockIdx.x < mgBlocks)
    conv_path_body(sm.p, blockIdx.x, actM, actG, Pm, Pg, BsM, BsG,
                   foutM, foutG, soutM, soutG, Cin, Cout, psIn, psOut, actMk, actGk);
  else
    conv_noise_body<MF, BNS, CIN>(sm.n, blockIdx.x - mgBlocks,
                                  nActIn, nAg, nBs, nActOut, nSin, nPsIn, nPsOut);
}

// -------------------------------------------------------------------------
// fold_all standalone (serial schedule only; runs after the m/g chain)
// -------------------------------------------------------------------------
__global__ void __launch_bounds__(256) fold_all(
    const float* __restrict__ nw0, const float* __restrict__ nw1,
    const float* __restrict__ nw2, const float* __restrict__ nw3,
    const float* __restrict__ nlw,
    short* __restrict__ E1, short* __restrict__ E2,
    short* __restrict__ E3, short* __restrict__ E4,
    short* __restrict__ Pnl)
{
  int i = blockIdx.x * 256 + threadIdx.x;
  if (i >= 106496) {
    if (i >= 108544) return;
    int idx = i - 106496;
    int co = idx >> 6, ci = (idx & 63) * 8;
    v8s hv[3], lv[3];
#pragma unroll
    for (int j = 0; j < 8; ++j)
#pragma unroll
      for (int tap = 0; tap < 3; ++tap) {
        float v = (co < 17) ? nlw[((size_t)(co * 512 + ci + j)) * 3 + tap] : 0.f;
        short h = bf16rne(v);
        hv[tap][j] = h;
        lv[tap][j] = bf16rne(v - bf16tof(h));
      }
#pragma unroll
    for (int tap = 0; tap < 3; ++tap) {
      *(v8s*)&Pnl[(size_t)(0 * 32 + co) * 1536 + tap * 512 + ci] = hv[tap];
      *(v8s*)&Pnl[(size_t)(1 * 32 + co) * 1536 + tap * 512 + ci] = lv[tap];
    }
    return;
  }
  const float* W; short* Ag; int Cin; int idx;
  if (i < 8192)        { W = nw0; Ag = E1; Cin = 128; idx = i; }
  else if (i < 40960)  { W = nw1; Ag = E2; Cin = 512; idx = i - 8192; }
  else if (i < 73728)  { W = nw2; Ag = E3; Cin = 512; idx = i - 40960; }
  else                 { W = nw3; Ag = E4; Cin = 512; idx = i - 73728; }
  const int nci8 = Cin >> 3;
  int co = idx / nci8, ci = (idx - co * nci8) * 8;
  const float* wp = W + (size_t)(co * Cin + ci) * 7;
  const int K = Cin * 4;
  v8s he[4], le[4], ho[4], lo4[4];
#pragma unroll
  for (int j = 0; j < 8; ++j) {
    const float* w = wp + j * 7;
    float fe[4] = {w[0],        w[1] + w[2], w[3] + w[4], w[5] + w[6]};
    float fo[4] = {w[0] + w[1], w[2] + w[3], w[4] + w[5], w[6]};
#pragma unroll
    for (int q = 0; q < 4; ++q) {
      short h1 = bf16rne(fe[q]);
      he[q][j] = h1; le[q][j] = bf16rne(fe[q] - bf16tof(h1));
      short h2 = bf16rne(fo[q]);
      ho[q][j] = h2; lo4[q][j] = bf16rne(fo[q] - bf16tof(h2));
    }
  }
#pragma unroll
  for (int q = 0; q < 4; ++q) {
    size_t kbase = (size_t)q * Cin + ci;
    *(v8s*)&Ag[((size_t)(0 * 512 + co)) * K + kbase] = he[q];
    *(v8s*)&Ag[((size_t)(1 * 512 + co)) * K + kbase] = le[q];
    *(v8s*)&Ag[((size_t)(2 * 512 + co)) * K + kbase] = ho[q];
    *(v8s*)&Ag[((size_t)(3 * 512 + co)) * K + kbase] = lo4[q];
  }
}

// -------------------------------------------------------------------------
// conv_nl (MFMA) fused with the noise-bank filter.
// -------------------------------------------------------------------------
#define NL_PS4 8388608   // l4act plane stride (shorts)

__global__ void __launch_bounds__(128) conv_nl_filter(
    const short* __restrict__ act, const short* __restrict__ Pnl,
    const float* __restrict__ Bs, const float* __restrict__ noise,
    float* __restrict__ filt)
{
  const int bid = blockIdx.x;
  const int b = bid >> 4, t0 = (bid & 15) << 6;
  const int tid = threadIdx.x;
  const int w = tid >> 6;
  const int l = tid & 63;

  __shared__ __align__(16) short Al[2 * 3 * 32 * 72];
  __shared__ __align__(16) short Bl[2 * 66 * 72];
  __shared__ float magS[64][20];
  __shared__ float ctS[32], stS[32];

  if (tid < 32) {
    double a = (double)tid * (3.14159265358979323846 / 16.0);
    ctS[tid] = (float)cos(a);
    stS[tid] = (float)sin(a);
  }

  f32x16 acc = {};

  for (int ci0 = 0; ci0 < 512; ci0 += 64) {
    for (int e = tid; e < 1536; e += 128) {
      int c8 = e & 7, row = e >> 3;
      int pl = row >= 96;
      int r2 = row - pl * 96;
      int tap = r2 >> 5, co = r2 & 31;
      v8s vv = *(const v8s*)&Pnl[(size_t)(pl * 32 + co) * 1536 + tap * 512 + ci0 + c8 * 8];
      *(v8s*)&Al[row * 72 + c8 * 8] = vv;
    }
    for (int e = tid; e < 1056; e += 128) {
      int c8 = e & 7, r = (e >> 3) % 66, pl = (e >> 3) / 66;
      int t = t0 + r - 1;
      v8s vv = {};
      if (t >= 0 && t < 1024)
        vv = *(const v8s*)&act[(size_t)pl * NL_PS4 + ((size_t)(b << 10) + t) * 512 + ci0 + c8 * 8];
      *(v8s*)&Bl[(pl * 66 + r) * 72 + c8 * 8] = vv;
    }
    __syncthreads();
    const int lr = l & 31, lh = (l >> 5) * 8;
#pragma unroll
    for (int kk = 0; kk < 4; ++kk)
#pragma unroll
      for (int tap = 0; tap < 3; ++tap) {
        v8s a_h = *(const v8s*)&Al[((0 * 3 + tap) * 32 + lr) * 72 + kk * 16 + lh];
        v8s a_l = *(const v8s*)&Al[((1 * 3 + tap) * 32 + lr) * 72 + kk * 16 + lh];
        int brow = w * 32 + lr + tap;
        v8s b_h = *(const v8s*)&Bl[(0 * 66 + brow) * 72 + kk * 16 + lh];
        v8s b_l = *(const v8s*)&Bl[(1 * 66 + brow) * 72 + kk * 16 + lh];
        acc = __builtin_amdgcn_mfma_f32_32x32x16_bf16(a_h, b_h, acc, 0, 0, 0);
        acc = __builtin_amdgcn_mfma_f32_32x32x16_bf16(a_h, b_l, acc, 0, 0, 0);
        acc = __builtin_amdgcn_mfma_f32_32x32x16_bf16(a_l, b_h, acc, 0, 0, 0);
      }
    __syncthreads();
  }

  const int t_loc = w * 32 + (l & 31);
  const int hi4 = 4 * (l >> 5);
#pragma unroll
  for (int q4 = 0; q4 < 4; ++q4)
#pragma unroll
    for (int j = 0; j < 4; ++j) {
      int co = q4 * 8 + hi4 + j;
      if (co < 17) {
        float z = acc[q4 * 4 + j] + Bs[co];
        magS[t_loc][co] = z * z;
      }
    }
  __syncthreads();

  if (tid < 64) {
    int i = t0 + tid;
    float xv[32];
#pragma unroll
    for (int n = 0; n < 32; ++n) {
      int idx = i * 16 + n;
      xv[n] = (idx < 16384) ? noise[(size_t)b * 16384 + idx] : 0.f;
    }
    float Yr[17], Yi[17];
#pragma unroll
    for (int k = 0; k <= 16; ++k) {
      float xr = 0.f, xi = 0.f;
      int kk = 0;
#pragma unroll
      for (int n = 0; n < 32; ++n) {
        xr += xv[n] * ctS[kk];
        xi -= xv[n] * stS[kk];
        kk = (kk + k) & 31;
      }
      float m = magS[tid][k];
      Yr[k] = xr * m;
      Yi[k] = xi * m;
    }
    float* fo = filt + ((size_t)(b << 10) + i) * 32;
#pragma unroll
    for (int n = 0; n < 32; ++n) {
      float v = Yr[0] + ((n & 1) ? -Yr[16] : Yr[16]);
      int kk = n;
#pragma unroll
      for (int k = 1; k <= 15; ++k) {
        v += 2.f * (Yr[k] * ctS[kk] - Yi[k] * stS[kk]);
        kk = (kk + n) & 31;
      }
      fo[n] = v * (1.f / 32.f);
    }
  }
}

// -------------------------------------------------------------------------
// Oscillator bank (3-point lerp endpoints + f64 chunk base + f32 Kahan).
// -------------------------------------------------------------------------
static __device__ __forceinline__ int clamp64(int i) { return i < 0 ? 0 : (i > 63 ? 63 : i); }

__global__ void __launch_bounds__(256) osc_phase(
    const float* __restrict__ fsm, double* __restrict__ phaseBase)
{
  const int o = blockIdx.x, b = blockIdx.y;
  const float* frow = fsm + (size_t)(b * 128 + o) * 64;
  const int c = threadIdx.x;

  const float ic0 = ((float)(c * 64) - 127.5f) * (1.0f / 256.0f);
  const int ilo = (int)floorf(ic0);
  float f0 = frow[clamp64(ilo)], f1 = frow[clamp64(ilo + 1)], f2 = frow[clamp64(ilo + 2)];

  double local = 0.0;
#pragma unroll 8
  for (int j = 0; j < 64; ++j) {
    float ic = ic0 + (float)j * (1.0f / 256.0f);
    float fl = floorf(ic);
    float w  = ic - fl;
    bool hi = ((int)fl) > ilo;
    float fa = hi ? f1 : f0;
    float fb = hi ? f2 : f1;
    float f = fa * (1.f - w) + fb * w;
    f = fminf(fmaxf(f, 20.f), 11025.f);
    local += (double)f;
  }
  local *= (1.0 / 22050.0);

  __shared__ double ps[256];
  ps[c] = local;
  __syncthreads();
  for (int off = 1; off < 256; off <<= 1) {
    double v = (c >= off) ? ps[c - off] : 0.0;
    __syncthreads();
    ps[c] += v;
    __syncthreads();
  }
  phaseBase[(size_t)(b * 128 + o) * 256 + c] = ps[c] - local;
}

__global__ void __launch_bounds__(128) osc_sum(
    const float* __restrict__ fsm, const float* __restrict__ lsm,
    const double* __restrict__ phaseBase, const float* __restrict__ filt,
    float* __restrict__ out)
{
  const int c = blockIdx.x, b = blockIdx.y;
  const int tid = threadIdx.x;
  __shared__ float contrib[128][65];
  __shared__ float part[2][64];
  const int o = tid;
  const float* frow = fsm + (size_t)(b * 128 + o) * 64;
  const float* arow = lsm + (size_t)(b * 128 + o) * 64;

  double pb = phaseBase[(size_t)(b * 128 + o) * 256 + c];
  float fb0 = (float)(pb - floor(pb));

  const float ic0 = ((float)(c * 64) - 127.5f) * (1.0f / 256.0f);
  const int ilo = (int)floorf(ic0);
  float f0 = frow[clamp64(ilo)], f1 = frow[clamp64(ilo + 1)], f2 = frow[clamp64(ilo + 2)];
  float a0 = arow[clamp64(ilo)], a1 = arow[clamp64(ilo + 1)], a2 = arow[clamp64(ilo + 2)];

  float rel = 0.f, comp = 0.f;
#pragma unroll 8
  for (int j = 0; j < 64; ++j) {
    float ic = ic0 + (float)j * (1.0f / 256.0f);
    float fl = floorf(ic);
    float w  = ic - fl;
    bool hi = ((int)fl) > ilo;
    float fa = hi ? f1 : f0;
    float fb = hi ? f2 : f1;
    float f = fa * (1.f - w) + fb * w;
    f = fminf(fmaxf(f, 20.f), 11025.f);
    float y = f * (1.0f / 22050.0f) - comp;
    float t = rel + y;
    comp = (t - rel) - y;
    rel = t;
    float tot = fb0 + rel;
    float frac = tot - floorf(tot);
    float s = sinpif(2.f * frac);
    float aa = hi ? a1 : a0;
    float ab = hi ? a2 : a1;
    float am = aa * (1.f - w) + ab * w;
    contrib[o][j] = s * am;
  }
  __syncthreads();
  int half = tid >> 6, tl = tid & 63;
  float sum = 0.f;
  for (int oo = 0; oo < 64; ++oo) sum += contrib[half * 64 + oo][tl];
  part[half][tl] = sum;
  __syncthreads();
  if (tid < 64) {
    int t = c * 64 + tid;
    float v = part[0][tid] + part[1][tid];
    int i0 = t >> 4, r = t & 15;
    v += filt[((size_t)(b << 10) + i0) * 32 + r];
    if (i0 > 0) v += filt[((size_t)(b << 10) + i0 - 1) * 32 + 16 + r];
    out[(size_t)b * 16384 + t] = v;
  }
}

// -------------------------------------------------------------------------
extern "C" void kernel_launch(void* const* d_in, const int* in_sizes, int n_in,
                              void* d_out, int out_size, void* d_ws, size_t ws_size,
                              hipStream_t stream)
{
  (void)in_sizes; (void)n_in; (void)out_size;

  const float* x     = (const float*)d_in[0];
  const float* noise = (const float*)d_in[1];
  const float* mw0 = (const float*)d_in[2];  const float* mb0 = (const float*)d_in[3];
  const float* mw1 = (const float*)d_in[4];  const float* mb1 = (const float*)d_in[5];
  const float* mw2 = (const float*)d_in[6];  const float* mb2 = (const float*)d_in[7];
  const float* mw3 = (const float*)d_in[8];  const float* mb3 = (const float*)d_in[9];
  const float* fw  = (const float*)d_in[10]; const float* fb  = (const float*)d_in[11];
  const float* gw0 = (const float*)d_in[12]; const float* gb0 = (const float*)d_in[13];
  const float* gw1 = (const float*)d_in[14]; const float* gb1 = (const float*)d_in[15];
  const float* gw2 = (const float*)d_in[16]; const float* gb2 = (const float*)d_in[17];
  const float* gw3 = (const float*)d_in[18]; const float* gb3 = (const float*)d_in[19];
  const float* lw  = (const float*)d_in[20]; const float* lb  = (const float*)d_in[21];
  const float* nw0 = (const float*)d_in[22]; const float* nb0 = (const float*)d_in[23];
  const float* nw1 = (const float*)d_in[24]; const float* nb1 = (const float*)d_in[25];
  const float* nw2 = (const float*)d_in[26]; const float* nb2 = (const float*)d_in[27];
  const float* nw3 = (const float*)d_in[28]; const float* nb3 = (const float*)d_in[29];
  const float* nlw = (const float*)d_in[30]; const float* nlb = (const float*)d_in[31];

  char* W8 = (char*)d_ws;
  float* out = (float*)d_out;
  const int PS_X = 131072;   // xm3 plane stride (shorts)
  const int PS_H = 524288;   // m/g act plane stride (shorts)

  const bool bigws = (ws_size >= 144113664ull);

  if (bigws) {
    // ======== OVERLAPPED schedule: fully disjoint layout (144.1 MB) ========
    short* mP  = (short*)(W8 + 0);
    short* gP  = (short*)(W8 + 16515072);
    short* hm0 = (short*)(W8 + 33030144);
    short* hm1 = (short*)(W8 + 36175872);
    short* hg0 = (short*)(W8 + 39321600);
    short* hg1 = (short*)(W8 + 42467328);
    short* xm3 = (short*)(W8 + 45613056);
    float* fsm = (float*)(W8 + 46399488);
    float* lsm = (float*)(W8 + 46923776);
    short* Pnl = (short*)(W8 + 47448064);
    short* E1  = (short*)(W8 + 47644672);
    short* E2  = (short*)(W8 + 49741824);
    short* E3  = (short*)(W8 + 58130432);
    short* E4  = (short*)(W8 + 66519040);
    short* l1out = (short*)(W8 + 74907648);
    short* l2out = (short*)(W8 + 79101952);
    short* l3out = (short*)(W8 + 87490560);
    short* l4act = (short*)(W8 + 104267776);
    float* filt  = (float*)(W8 + 137822208);
    double* phaseBase = (double*)(W8 + 139919360);

    prep_all<<<1832, 256, 0, stream>>>(x, xm3,
        mw0, mw1, mw2, mw3, fw, gw0, gw1, gw2, gw3, lw, mP, gP,
        nw0, nw1, nw2, nw3, nlw, E1, E2, E3, E4, Pnl);

    // mg_i co-launched with noise_i (independent chains)
    k_fused<1, 64, 128><<<512, 256, 0, stream>>>(
        xm3, xm3, mP + 0, gP + 0, mb0, gb0, nullptr, nullptr, hm0, hg0,
        128, 512, PS_X, PS_H, ACT_LRELU, ACT_LRELU,
        xm3, E1, nb0, l1out, 64, PS_X, 1048576, 256);
    k_fused<2, 64, 512><<<512, 256, 0, stream>>>(
        hm0, hg0, mP + 589824, gP + 589824, mb1, gb1, nullptr, nullptr, hm1, hg1,
        512, 512, PS_H, PS_H, ACT_LRELU, ACT_LRELU,
        l1out, E2, nb1, l2out, 128, 1048576, 2097152, 256);
    k_fused<2, 128, 512><<<512, 256, 0, stream>>>(
        hm1, hg1, mP + 2949120, gP + 2949120, mb2, gb2, nullptr, nullptr, hm0, hg0,
        512, 512, PS_H, PS_H, ACT_LRELU, ACT_LRELU,
        l2out, E3, nb2, l3out, 256, 2097152, 4194304, 256);
    k_fused<2, 128, 512><<<768, 256, 0, stream>>>(
        hm0, hg0, mP + 5308416, gP + 5308416, mb3, gb3, nullptr, nullptr, hm1, hg1,
        512, 512, PS_H, PS_H, ACT_LRELU, ACT_LRELU,
        l3out, E4, nb3, l4act, 512, 4194304, 8388608, 256);

    k_conv_path<<<64, 256, 0, stream>>>(hm1, hg1, mP + 7667712, gP + 7667712, fb, lb,
        fsm, lsm, nullptr, nullptr, 512, 128, PS_H, 0, ACT_SIGMAP, ACT_SQUARE);

    conv_nl_filter<<<256, 128, 0, stream>>>(l4act, Pnl, nlb, noise, filt);
    osc_phase<<<dim3(128, 16), 256, 0, stream>>>(fsm, phaseBase);
    osc_sum<<<dim3(256, 16), 128, 0, stream>>>(fsm, lsm, phaseBase, filt, out);
  } else {
    // ======== SERIAL schedule: proven round-12 layout + liveness ========
    short* mP  = (short*)(W8 + 0);
    short* gP  = (short*)(W8 + 16515072);
    short* hm0 = (short*)(W8 + 33030144);
    short* hm1 = (short*)(W8 + 36175872);
    short* hg0 = (short*)(W8 + 39321600);
    short* hg1 = (short*)(W8 + 42467328);
    short* xm3 = (short*)(W8 + 58720256);
    float* fsm = (float*)(W8 + 59506688);
    float* lsm = (float*)(W8 + 60030976);
    short* Pnl = (short*)(W8 + 60555264);

    short* E4  = (short*)(W8 + 0);
    short* E3  = (short*)(W8 + 33554432);
    short* E2  = (short*)(W8 + 41943040);
    short* E1  = (short*)(W8 + 50331648);
    short* l1out = (short*)(W8 + 52428800);
    short* l2out = (short*)(W8 + 25165824);
    short* l3out = (short*)(W8 + 8388608);
    short* l4act = (short*)(W8 + 25165824);

    float* filt = (float*)(W8 + 1114112);
    double* phaseBase = (double*)(W8 + 4194304);

    // prep (acts + m/g panels only; fold deferred — aliases live memory)
    prep_all<<<1408, 256, 0, stream>>>(x, xm3,
        mw0, mw1, mw2, mw3, fw, gw0, gw1, gw2, gw3, lw, mP, gP,
        nw0, nw1, nw2, nw3, nlw, E1, E2, E3, E4, Pnl);

    k_conv_path<<<256, 256, 0, stream>>>(xm3, xm3, mP + 0, gP + 0, mb0, gb0,
        nullptr, nullptr, hm0, hg0, 128, 512, PS_X, PS_H, ACT_LRELU, ACT_LRELU);
    k_conv_path<<<256, 256, 0, stream>>>(hm0, hg0, mP + 589824, gP + 589824, mb1, gb1,
        nullptr, nullptr, hm1, hg1, 512, 512, PS_H, PS_H, ACT_LRELU, ACT_LRELU);
    k_conv_path<<<256, 256, 0, stream>>>(hm1, hg1, mP + 2949120, gP + 2949120, mb2, gb2,
        nullptr, nullptr, hm0, hg0, 512, 512, PS_H, PS_H, ACT_LRELU, ACT_LRELU);
    k_conv_path<<<256, 256, 0, stream>>>(hm0, hg0, mP + 5308416, gP + 5308416, mb3, gb3,
        nullptr, nullptr, hm1, hg1, 512, 512, PS_H, PS_H, ACT_LRELU, ACT_LRELU);
    k_conv_path<<<64, 256, 0, stream>>>(hm1, hg1, mP + 7667712, gP + 7667712, fb, lb,
        fsm, lsm, nullptr, nullptr, 512, 128, PS_H, 0, ACT_SIGMAP, ACT_SQUARE);

    fold_all<<<424, 256, 0, stream>>>(nw0, nw1, nw2, nw3, nlw, E1, E2, E3, E4, Pnl);
    k_conv_noise<1, 64, 128><<<256, 256, 0, stream>>>(xm3, E1, nb0, l1out, 64, PS_X, 1048576);
    k_conv_noise<2, 64, 512><<<256, 256, 0, stream>>>(l1out, E2, nb1, l2out, 128, 1048576, 2097152);
    k_conv_noise<2, 128, 512><<<256, 256, 0, stream>>>(l2out, E3, nb2, l3out, 256, 2097152, 4194304);
    k_conv_noise<2, 128, 512><<<512, 256, 0, stream>>>(l3out, E4, nb3, l4act, 512, 4194304, 8388608);

    conv_nl_filter<<<256, 128, 0, stream>>>(l4act, Pnl, nlb, noise, filt);
    osc_phase<<<dim3(128, 16), 256, 0, stream>>>(fsm, phaseBase);
    osc_sum<<<dim3(256, 16), 128, 0, stream>>>(fsm, lsm, phaseBase, filt, out);
  }
}

// Round 15
// 507.402 us; speedup vs baseline: 1.4210x; 1.4210x over previous
//
#include <hip/hip_runtime.h>
#include <math.h>

#define ACT_LRELU  0
#define ACT_SIGMAP 1
#define ACT_SQUARE 2

typedef __attribute__((ext_vector_type(8))) short v8s;
typedef __attribute__((ext_vector_type(4))) short v4s;
typedef __attribute__((ext_vector_type(16))) float f32x16;

static __device__ __forceinline__ float lrelu(float x) { return x >= 0.f ? x : 0.2f * x; }

static __device__ __forceinline__ short bf16rne(float x) {
  unsigned u = __float_as_uint(x);
  unsigned r = (u + 0x7FFFu + ((u >> 16) & 1u)) >> 16;
  return (short)r;
}
static __device__ __forceinline__ float bf16tof(short h) {
  return __uint_as_float(((unsigned)(unsigned short)h) << 16);
}
static __device__ __forceinline__ void split3(float v, short& h, short& l, short& q) {
  h = bf16rne(v); float r1 = v - bf16tof(h);
  l = bf16rne(r1); float r2 = r1 - bf16tof(l);
  q = bf16rne(r2);
}

// -------------------------------------------------------------------------
// prep_all: block-range dispatch.
//  [0,512)      prep_acts:   x -> xm3 3-plane bf16 [pl][b][t][ci]
//  [512,1408)   prep_panels: m/g weights -> 3-plane tap-major panels
//  [1408,1832)  fold: noise weights -> folded parity hi/lo panels + Pnl
// Disjoint-layout schedule launches 1832 blocks (fold included — no alias).
// Aliased (small-ws) schedule launches 1408 only; fold runs separately
// after the m/g chain (E-panels alias live phase-A memory).
// -------------------------------------------------------------------------
__global__ void __launch_bounds__(256) prep_all(
    const float* __restrict__ x, short* __restrict__ xm3,
    const float* mw0, const float* mw1, const float* mw2, const float* mw3, const float* fw,
    const float* gw0, const float* gw1, const float* gw2, const float* gw3, const float* lw,
    short* __restrict__ mP, short* __restrict__ gP,
    const float* __restrict__ nw0, const float* __restrict__ nw1,
    const float* __restrict__ nw2, const float* __restrict__ nw3,
    const float* __restrict__ nlw,
    short* __restrict__ E1, short* __restrict__ E2,
    short* __restrict__ E3, short* __restrict__ E4,
    short* __restrict__ Pnl)
{
  const int blk = blockIdx.x;
  const int tid = threadIdx.x;

  if (blk < 512) {
    int e = blk * 256 + tid;
    if (e >= 131072) return;
    int b = e >> 13, rem = e & 8191, t = rem >> 7, ci = rem & 127;
    float v = x[((size_t)(b * 128) + ci) * 64 + t];
    short h, l, q; split3(v, h, l, q);
    size_t o = ((size_t)(b * 64) + t) * 128 + ci;
    xm3[0 * 131072 + o] = h;
    xm3[1 * 131072 + o] = l;
    xm3[2 * 131072 + o] = q;
    return;
  }

  if (blk < 1408) {
    int i = (blk - 512) * 256 + tid;
    const int PER = 114688;
    if (i >= 2 * PER) return;
    int path = i >= PER ? 1 : 0;
    int r = i - path * PER;
    int Cin, Cout; size_t poff;
    const float* W;
    {
      int layer;
      if (r < 8192)        { layer = 0;              Cin = 128; Cout = 512; poff = 0; }
      else if (r < 40960)  { layer = 1; r -= 8192;   Cin = 512; Cout = 512; poff = 589824; }
      else if (r < 73728)  { layer = 2; r -= 40960;  Cin = 512; Cout = 512; poff = 2949120; }
      else if (r < 106496) { layer = 3; r -= 73728;  Cin = 512; Cout = 512; poff = 5308416; }
      else                 { layer = 4; r -= 106496; Cin = 512; Cout = 128; poff = 7667712; }
      const float* Wm[5] = {mw0, mw1, mw2, mw3, fw};
      const float* Wg[5] = {gw0, gw1, gw2, gw3, lw};
      W = path ? Wg[layer] : Wm[layer];
    }
    short* P = (path ? gP : mP) + poff;
    const int nci8 = Cin >> 3;
    int co = r / nci8, ci = (r - co * nci8) * 8;
    const int K3 = 3 * Cin;
    const float* wp = W + (size_t)(co * Cin + ci) * 3;
    v8s hv[3], lv[3], qv[3];
#pragma unroll
    for (int j = 0; j < 8; ++j)
#pragma unroll
      for (int tap = 0; tap < 3; ++tap) {
        short h, l, q; split3(wp[j * 3 + tap], h, l, q);
        hv[tap][j] = h; lv[tap][j] = l; qv[tap][j] = q;
      }
#pragma unroll
    for (int tap = 0; tap < 3; ++tap) {
      size_t base = (size_t)co * K3 + tap * Cin + ci;
      *(v8s*)&P[(size_t)0 * Cout * K3 + base] = hv[tap];
      *(v8s*)&P[(size_t)1 * Cout * K3 + base] = lv[tap];
      *(v8s*)&P[(size_t)2 * Cout * K3 + base] = qv[tap];
    }
    return;
  }

  // ---- fold range ----
  int i = (blk - 1408) * 256 + tid;
  if (i >= 106496) {
    if (i >= 108544) return;
    int idx = i - 106496;
    int co = idx >> 6, ci = (idx & 63) * 8;
    v8s hv[3], lv[3];
#pragma unroll
    for (int j = 0; j < 8; ++j)
#pragma unroll
      for (int tap = 0; tap < 3; ++tap) {
        float v = (co < 17) ? nlw[((size_t)(co * 512 + ci + j)) * 3 + tap] : 0.f;
        short h = bf16rne(v);
        hv[tap][j] = h;
        lv[tap][j] = bf16rne(v - bf16tof(h));
      }
#pragma unroll
    for (int tap = 0; tap < 3; ++tap) {
      *(v8s*)&Pnl[(size_t)(0 * 32 + co) * 1536 + tap * 512 + ci] = hv[tap];
      *(v8s*)&Pnl[(size_t)(1 * 32 + co) * 1536 + tap * 512 + ci] = lv[tap];
    }
    return;
  }
  const float* W; short* Ag; int Cin; int idx;
  if (i < 8192)        { W = nw0; Ag = E1; Cin = 128; idx = i; }
  else if (i < 40960)  { W = nw1; Ag = E2; Cin = 512; idx = i - 8192; }
  else if (i < 73728)  { W = nw2; Ag = E3; Cin = 512; idx = i - 40960; }
  else                 { W = nw3; Ag = E4; Cin = 512; idx = i - 73728; }
  const int nci8 = Cin >> 3;
  int co = idx / nci8, ci = (idx - co * nci8) * 8;
  const float* wp = W + (size_t)(co * Cin + ci) * 7;
  const int K = Cin * 4;
  v8s he[4], le[4], ho[4], lo4[4];
#pragma unroll
  for (int j = 0; j < 8; ++j) {
    const float* w = wp + j * 7;
    float fe[4] = {w[0],        w[1] + w[2], w[3] + w[4], w[5] + w[6]};
    float fo[4] = {w[0] + w[1], w[2] + w[3], w[4] + w[5], w[6]};
#pragma unroll
    for (int q = 0; q < 4; ++q) {
      short h1 = bf16rne(fe[q]);
      he[q][j] = h1; le[q][j] = bf16rne(fe[q] - bf16tof(h1));
      short h2 = bf16rne(fo[q]);
      ho[q][j] = h2; lo4[q][j] = bf16rne(fo[q] - bf16tof(h2));
    }
  }
#pragma unroll
  for (int q = 0; q < 4; ++q) {
    size_t kbase = (size_t)q * Cin + ci;
    *(v8s*)&Ag[((size_t)(0 * 512 + co)) * K + kbase] = he[q];
    *(v8s*)&Ag[((size_t)(1 * 512 + co)) * K + kbase] = le[q];
    *(v8s*)&Ag[((size_t)(2 * 512 + co)) * K + kbase] = ho[q];
    *(v8s*)&Ag[((size_t)(3 * 512 + co)) * K + kbase] = lo4[q];
  }
}

// -------------------------------------------------------------------------
// m/g path conv: 3-plane split-bf16 MFMA GEMM, 32x32x16, ~fp32 precision,
// T14 async staging. Single kernel per layer (activation + split fused).
// (Verbatim round-12 kernel — proven 0-conflict codegen.)
// -------------------------------------------------------------------------
__global__ void __launch_bounds__(256, 2) conv_path(
    const short* __restrict__ actM, const short* __restrict__ actG,
    const short* __restrict__ Pm, const short* __restrict__ Pg,
    const float* __restrict__ BsM, const float* __restrict__ BsG,
    float* __restrict__ foutM, float* __restrict__ foutG,
    short* __restrict__ soutM, short* __restrict__ soutG,
    int Cin, int Cout, int psIn, int psOut, int actMk, int actGk)
{
  const int mtiles = Cout >> 6;
  const int nblk = 2 * mtiles * 16;
  const int Q = nblk >> 3;
  int d = blockIdx.x;
  int idx = (d & 7) * Q + (d >> 3);
  int mt = idx % mtiles;
  int tmp = idx / mtiles;
  int nt = tmp & 15;
  int path = tmp >> 4;

  const short* act = path ? actG : actM;
  const short* P   = path ? Pg : Pm;
  const float* Bs  = path ? BsG : BsM;
  float* fout      = path ? foutG : foutM;
  short* sout      = path ? soutG : soutM;
  const int actk   = path ? actGk : actMk;

  const int K3 = 3 * Cin;
  const int co0 = mt * 64;
  const int n0  = nt * 64;
  const int nci = Cin >> 6;
  const int NT  = 3 * nci;

  const int tid = threadIdx.x;
  const int w = tid >> 6, wm = w & 1, wn = w >> 1;
  const int l = tid & 63;

  __shared__ __align__(16) short Al[3][64 * 72];
  __shared__ __align__(16) short Bl[3][64 * 72];
  __shared__ float bandS[2][128];

  if (actk == ACT_SIGMAP && tid < 128) {
    double lg = log(551.25);
    double stop  = 20.0 * exp(lg * (double)tid / 127.0);
    double start = (tid == 0) ? 0.0 : 20.0 * exp(lg * (double)(tid - 1) / 127.0);
    bandS[0][tid] = (float)start;
    bandS[1][tid] = (float)(stop - start);
  }

  f32x16 acc = {};
  v8s rA[3][2], rB[3][2];

  auto LOADA = [&](int t) {
    int tap = t / nci, ci0 = (t % nci) << 6;
#pragma unroll
    for (int pl = 0; pl < 3; ++pl)
#pragma unroll
      for (int it = 0; it < 2; ++it) {
        int e = it * 256 + tid;
        int row = e >> 3, c8 = e & 7;
        rA[pl][it] = *(const v8s*)&P[(size_t)pl * Cout * K3 + (size_t)(co0 + row) * K3
                                     + tap * Cin + ci0 + c8 * 8];
      }
  };
  auto LOADB = [&](int t) {
    int tap = t / nci, ci0 = (t % nci) << 6;
#pragma unroll
    for (int pl = 0; pl < 3; ++pl)
#pragma unroll
      for (int it = 0; it < 2; ++it) {
        int e = it * 256 + tid;
        int n = e >> 3, c8 = e & 7;
        int gn = n0 + n, bb = gn >> 6, trow = (gn & 63) + tap - 1;
        v8s vv = {};
        if (trow >= 0 && trow < 64)
          vv = *(const v8s*)&act[(size_t)pl * psIn + ((size_t)(bb * 64 + trow)) * Cin
                                 + ci0 + c8 * 8];
        rB[pl][it] = vv;
      }
  };
  auto WRITE = [&]() {
#pragma unroll
    for (int pl = 0; pl < 3; ++pl)
#pragma unroll
      for (int it = 0; it < 2; ++it) {
        int e = it * 256 + tid;
        int row = e >> 3, c8 = e & 7;
        *(v8s*)&Al[pl][row * 72 + c8 * 8] = rA[pl][it];
        *(v8s*)&Bl[pl][row * 72 + c8 * 8] = rB[pl][it];
      }
  };

  LOADA(0); LOADB(0);
  WRITE();
  __syncthreads();

  for (int t = 0; t < NT; ++t) {
    if (t + 1 < NT) { LOADA(t + 1); LOADB(t + 1); }
    const int abase = (wm * 32 + (l & 31)) * 72 + (l >> 5) * 8;
    const int bbase = (wn * 32 + (l & 31)) * 72 + (l >> 5) * 8;
#pragma unroll
    for (int kk = 0; kk < 4; ++kk) {
      v8s a0 = *(const v8s*)&Al[0][abase + kk * 16];
      v8s a1 = *(const v8s*)&Al[1][abase + kk * 16];
      v8s a2 = *(const v8s*)&Al[2][abase + kk * 16];
      v8s b0 = *(const v8s*)&Bl[0][bbase + kk * 16];
      v8s b1 = *(const v8s*)&Bl[1][bbase + kk * 16];
      v8s b2 = *(const v8s*)&Bl[2][bbase + kk * 16];
      acc = __builtin_amdgcn_mfma_f32_32x32x16_bf16(a0, b0, acc, 0, 0, 0);
      acc = __builtin_amdgcn_mfma_f32_32x32x16_bf16(a0, b1, acc, 0, 0, 0);
      acc = __builtin_amdgcn_mfma_f32_32x32x16_bf16(a1, b0, acc, 0, 0, 0);
      acc = __builtin_amdgcn_mfma_f32_32x32x16_bf16(a1, b1, acc, 0, 0, 0);
      acc = __builtin_amdgcn_mfma_f32_32x32x16_bf16(a0, b2, acc, 0, 0, 0);
      acc = __builtin_amdgcn_mfma_f32_32x32x16_bf16(a2, b0, acc, 0, 0, 0);
    }
    __syncthreads();
    if (t + 1 < NT) { WRITE(); __syncthreads(); }
  }

  // epilogue: C/D layout col=lane&31, row=(r&3)+8*(r>>2)+4*(lane>>5)
  const int ncol = wn * 32 + (l & 31);
  const int gn = n0 + ncol, bb = gn >> 6, t = gn & 63;
  const int hi4 = 4 * (l >> 5);
#pragma unroll
  for (int q4 = 0; q4 < 4; ++q4) {
    int co = co0 + wm * 32 + q4 * 8 + hi4;
    float4 bia = *(const float4*)&Bs[co];
    const float* bp = &bia.x;
    float z[4];
#pragma unroll
    for (int j = 0; j < 4; ++j) z[j] = acc[q4 * 4 + j] + bp[j];
    if (actk == ACT_LRELU) {
      v4s h4, l4, q4v;
#pragma unroll
      for (int j = 0; j < 4; ++j) {
        float zz = lrelu(z[j]);
        short h, lo, qq; split3(zz, h, lo, qq);
        h4[j] = h; l4[j] = lo; q4v[j] = qq;
      }
      size_t o = ((size_t)(bb * 64) + t) * Cout + co;
      *(v4s*)&sout[0 * (size_t)psOut + o] = h4;
      *(v4s*)&sout[1 * (size_t)psOut + o] = l4;
      *(v4s*)&sout[2 * (size_t)psOut + o] = q4v;
    } else if (actk == ACT_SIGMAP) {
#pragma unroll
      for (int j = 0; j < 4; ++j) {
        float f = bandS[0][co + j] + bandS[1][co + j] / (1.f + expf(-z[j]));
        fout[((size_t)(bb * 128) + co + j) * 64 + t] = f;
      }
    } else {
#pragma unroll
      for (int j = 0; j < 4; ++j)
        fout[((size_t)(bb * 128) + co + j) * 64 + t] = z[j] * z[j];
    }
  }
}

// -------------------------------------------------------------------------
// Noise conv: ci-OUTER / q-INNER with shared B-slab (B staged once per ci0).
// 2-plane split-bf16 (hh,hl,lh), 32x32x16, T14 reg staging.
// (Verbatim round-12 kernel — proven 0-conflict codegen.)
// -------------------------------------------------------------------------
template<int MF, int BNS, int CIN>
__global__ void __launch_bounds__(256, 2) conv_noise(
    const short* __restrict__ actIn, const short* __restrict__ Ag,
    const float* __restrict__ Bs, short* __restrict__ actOut,
    int Sin, int psIn, int psOut)
{
  constexpr int NF   = BNS / 64;
  constexpr int BM   = MF * 64;
  constexpr int AITS = BM / 32;
  constexpr int SLAB = BNS + 3;
  constexpr int BSL  = (2 * SLAB * 8 + 255) / 256;
  constexpr int K    = CIN * 4;
  constexpr int nci  = CIN / 64;
  const int mtiles = 512 / BM;
  const int stiles = Sin / BNS;
  const int nblk = mtiles * 2 * 16 * stiles;
  const int Q = nblk >> 3;
  int d = blockIdx.x;
  int idx = (d & 7) * Q + (d >> 3);
  int mt = idx % mtiles;
  int t1 = idx / mtiles;
  int par = t1 & 1;
  int rest = t1 >> 1;
  int st = rest % stiles;
  int b = rest / stiles;

  const int co0 = mt * BM;
  const int s0 = st * BNS;
  const int soff = par ? -1 : -2;

  const int tid = threadIdx.x;
  const int w = tid >> 6, wm = w & 1, wn = w >> 1;
  const int l = tid & 63;

  __shared__ __align__(16) short Al[2][BM * 72];
  __shared__ __align__(16) short Bl[2][SLAB * 72];

  f32x16 acc[MF][NF] = {};
  v8s rA[2][AITS];
  v8s rBS[BSL];

  auto LOADA = [&](int q, int ci0) {
#pragma unroll
    for (int pl = 0; pl < 2; ++pl)
#pragma unroll
      for (int it = 0; it < AITS; ++it) {
        int e = it * 256 + tid;
        int row = e >> 3, c8 = e & 7;
        rA[pl][it] = *(const v8s*)&Ag[((size_t)((par * 2 + pl) * 512 + co0 + row)) * K
                                      + q * CIN + ci0 + c8 * 8];
      }
  };
  auto WRITEA = [&]() {
#pragma unroll
    for (int pl = 0; pl < 2; ++pl)
#pragma unroll
      for (int it = 0; it < AITS; ++it) {
        int e = it * 256 + tid;
        *(v8s*)&Al[pl][(e >> 3) * 72 + (e & 7) * 8] = rA[pl][it];
      }
  };
  auto LOADBS = [&](int ci0) {
#pragma unroll
    for (int it = 0; it < BSL; ++it) {
      int e = it * 256 + tid;
      v8s vv = {};
      if (e < 2 * SLAB * 8) {
        int r3 = e >> 3, c8 = e & 7;
        int pl = r3 / SLAB, row = r3 - pl * SLAB;
        int srow = s0 + soff + row;
        if (srow >= 0 && srow < Sin)
          vv = *(const v8s*)&actIn[(size_t)pl * psIn + ((size_t)(b * Sin + srow)) * CIN
                                   + ci0 + c8 * 8];
      }
      rBS[it] = vv;
    }
  };
  auto WRITEBS = [&]() {
#pragma unroll
    for (int it = 0; it < BSL; ++it) {
      int e = it * 256 + tid;
      if (e < 2 * SLAB * 8) {
        int r3 = e >> 3, c8 = e & 7;
        int pl = r3 / SLAB, row = r3 - pl * SLAB;
        *(v8s*)&Bl[pl][row * 72 + c8 * 8] = rBS[it];
      }
    }
  };

  LOADBS(0); LOADA(0, 0);
  WRITEBS(); WRITEA();
  __syncthreads();

  for (int ci = 0; ci < nci; ++ci) {
    const int ci0 = ci << 6;
#pragma unroll
    for (int q = 0; q < 4; ++q) {
      const bool lastq = (q == 3);
      const bool lastall = lastq && (ci == nci - 1);
      if (!lastq)        LOADA(q + 1, ci0);
      else if (!lastall) { LOADBS(ci0 + 64); LOADA(0, ci0 + 64); }

      const int lr = l & 31, lh = (l >> 5) * 8;
#pragma unroll
      for (int kk = 0; kk < 4; ++kk) {
        v8s ah[MF], al[MF], bh[NF], bl[NF];
#pragma unroll
        for (int fm = 0; fm < MF; ++fm) {
          int ab = (wm * (MF * 32) + fm * 32 + lr) * 72 + kk * 16 + lh;
          ah[fm] = *(const v8s*)&Al[0][ab];
          al[fm] = *(const v8s*)&Al[1][ab];
        }
#pragma unroll
        for (int fn = 0; fn < NF; ++fn) {
          int bb = (wn * (BNS / 2) + fn * 32 + lr + q) * 72 + kk * 16 + lh;
          bh[fn] = *(const v8s*)&Bl[0][bb];
          bl[fn] = *(const v8s*)&Bl[1][bb];
        }
#pragma unroll
        for (int fm = 0; fm < MF; ++fm)
#pragma unroll
          for (int fn = 0; fn < NF; ++fn) {
            acc[fm][fn] = __builtin_amdgcn_mfma_f32_32x32x16_bf16(ah[fm], bh[fn], acc[fm][fn], 0, 0, 0);
            acc[fm][fn] = __builtin_amdgcn_mfma_f32_32x32x16_bf16(ah[fm], bl[fn], acc[fm][fn], 0, 0, 0);
            acc[fm][fn] = __builtin_amdgcn_mfma_f32_32x32x16_bf16(al[fm], bh[fn], acc[fm][fn], 0, 0, 0);
          }
      }
      __syncthreads();
      if (!lastall) {
        if (!lastq) WRITEA();
        else { WRITEBS(); WRITEA(); }
        __syncthreads();
      }
    }
  }

  // epilogue: 2-plane bf16 [pl][b][t=2s+par][512]
  const int hi4 = 4 * (l >> 5);
  const int T2 = 2 * Sin;
#pragma unroll
  for (int fm = 0; fm < MF; ++fm)
#pragma unroll
    for (int q4 = 0; q4 < 4; ++q4) {
      int co = co0 + wm * (MF * 32) + fm * 32 + q4 * 8 + hi4;
      float4 bia = *(const float4*)&Bs[co];
      const float* bp = &bia.x;
#pragma unroll
      for (int fn = 0; fn < NF; ++fn) {
        int s_l = wn * (BNS / 2) + fn * 32 + (l & 31);
        int t = 2 * (s0 + s_l) + par;
        v4s h4, l4;
#pragma unroll
        for (int j = 0; j < 4; ++j) {
          float z = lrelu(acc[fm][fn][q4 * 4 + j] + bp[j]);
          short h = bf16rne(z);
          h4[j] = h;
          l4[j] = bf16rne(z - bf16tof(h));
        }
        size_t o = ((size_t)(b * T2) + t) * 512 + co;
        *(v4s*)&actOut[0 * (size_t)psOut + o] = h4;
        *(v4s*)&actOut[1 * (size_t)psOut + o] = l4;
      }
    }
}

// -------------------------------------------------------------------------
// fold_all standalone (small-ws schedule only; runs after the m/g chain)
// -------------------------------------------------------------------------
__global__ void __launch_bounds__(256) fold_all(
    const float* __restrict__ nw0, const float* __restrict__ nw1,
    const float* __restrict__ nw2, const float* __restrict__ nw3,
    const float* __restrict__ nlw,
    short* __restrict__ E1, short* __restrict__ E2,
    short* __restrict__ E3, short* __restrict__ E4,
    short* __restrict__ Pnl)
{
  int i = blockIdx.x * 256 + threadIdx.x;
  if (i >= 106496) {
    if (i >= 108544) return;
    int idx = i - 106496;
    int co = idx >> 6, ci = (idx & 63) * 8;
    v8s hv[3], lv[3];
#pragma unroll
    for (int j = 0; j < 8; ++j)
#pragma unroll
      for (int tap = 0; tap < 3; ++tap) {
        float v = (co < 17) ? nlw[((size_t)(co * 512 + ci + j)) * 3 + tap] : 0.f;
        short h = bf16rne(v);
        hv[tap][j] = h;
        lv[tap][j] = bf16rne(v - bf16tof(h));
      }
#pragma unroll
    for (int tap = 0; tap < 3; ++tap) {
      *(v8s*)&Pnl[(size_t)(0 * 32 + co) * 1536 + tap * 512 + ci] = hv[tap];
      *(v8s*)&Pnl[(size_t)(1 * 32 + co) * 1536 + tap * 512 + ci] = lv[tap];
    }
    return;
  }
  const float* W; short* Ag; int Cin; int idx;
  if (i < 8192)        { W = nw0; Ag = E1; Cin = 128; idx = i; }
  else if (i < 40960)  { W = nw1; Ag = E2; Cin = 512; idx = i - 8192; }
  else if (i < 73728)  { W = nw2; Ag = E3; Cin = 512; idx = i - 40960; }
  else                 { W = nw3; Ag = E4; Cin = 512; idx = i - 73728; }
  const int nci8 = Cin >> 3;
  int co = idx / nci8, ci = (idx - co * nci8) * 8;
  const float* wp = W + (size_t)(co * Cin + ci) * 7;
  const int K = Cin * 4;
  v8s he[4], le[4], ho[4], lo4[4];
#pragma unroll
  for (int j = 0; j < 8; ++j) {
    const float* w = wp + j * 7;
    float fe[4] = {w[0],        w[1] + w[2], w[3] + w[4], w[5] + w[6]};
    float fo[4] = {w[0] + w[1], w[2] + w[3], w[4] + w[5], w[6]};
#pragma unroll
    for (int q = 0; q < 4; ++q) {
      short h1 = bf16rne(fe[q]);
      he[q][j] = h1; le[q][j] = bf16rne(fe[q] - bf16tof(h1));
      short h2 = bf16rne(fo[q]);
      ho[q][j] = h2; lo4[q][j] = bf16rne(fo[q] - bf16tof(h2));
    }
  }
#pragma unroll
  for (int q = 0; q < 4; ++q) {
    size_t kbase = (size_t)q * Cin + ci;
    *(v8s*)&Ag[((size_t)(0 * 512 + co)) * K + kbase] = he[q];
    *(v8s*)&Ag[((size_t)(1 * 512 + co)) * K + kbase] = le[q];
    *(v8s*)&Ag[((size_t)(2 * 512 + co)) * K + kbase] = ho[q];
    *(v8s*)&Ag[((size_t)(3 * 512 + co)) * K + kbase] = lo4[q];
  }
}

// -------------------------------------------------------------------------
// conv_nl (MFMA) fused with the noise-bank filter.
// -------------------------------------------------------------------------
#define NL_PS4 8388608   // l4act plane stride (shorts)

__global__ void __launch_bounds__(128) conv_nl_filter(
    const short* __restrict__ act, const short* __restrict__ Pnl,
    const float* __restrict__ Bs, const float* __restrict__ noise,
    float* __restrict__ filt)
{
  const int bid = blockIdx.x;
  const int b = bid >> 4, t0 = (bid & 15) << 6;
  const int tid = threadIdx.x;
  const int w = tid >> 6;
  const int l = tid & 63;

  __shared__ __align__(16) short Al[2 * 3 * 32 * 72];
  __shared__ __align__(16) short Bl[2 * 66 * 72];
  __shared__ float magS[64][20];
  __shared__ float ctS[32], stS[32];

  if (tid < 32) {
    double a = (double)tid * (3.14159265358979323846 / 16.0);
    ctS[tid] = (float)cos(a);
    stS[tid] = (float)sin(a);
  }

  f32x16 acc = {};

  for (int ci0 = 0; ci0 < 512; ci0 += 64) {
    for (int e = tid; e < 1536; e += 128) {
      int c8 = e & 7, row = e >> 3;
      int pl = row >= 96;
      int r2 = row - pl * 96;
      int tap = r2 >> 5, co = r2 & 31;
      v8s vv = *(const v8s*)&Pnl[(size_t)(pl * 32 + co) * 1536 + tap * 512 + ci0 + c8 * 8];
      *(v8s*)&Al[row * 72 + c8 * 8] = vv;
    }
    for (int e = tid; e < 1056; e += 128) {
      int c8 = e & 7, r = (e >> 3) % 66, pl = (e >> 3) / 66;
      int t = t0 + r - 1;
      v8s vv = {};
      if (t >= 0 && t < 1024)
        vv = *(const v8s*)&act[(size_t)pl * NL_PS4 + ((size_t)(b << 10) + t) * 512 + ci0 + c8 * 8];
      *(v8s*)&Bl[(pl * 66 + r) * 72 + c8 * 8] = vv;
    }
    __syncthreads();
    const int lr = l & 31, lh = (l >> 5) * 8;
#pragma unroll
    for (int kk = 0; kk < 4; ++kk)
#pragma unroll
      for (int tap = 0; tap < 3; ++tap) {
        v8s a_h = *(const v8s*)&Al[((0 * 3 + tap) * 32 + lr) * 72 + kk * 16 + lh];
        v8s a_l = *(const v8s*)&Al[((1 * 3 + tap) * 32 + lr) * 72 + kk * 16 + lh];
        int brow = w * 32 + lr + tap;
        v8s b_h = *(const v8s*)&Bl[(0 * 66 + brow) * 72 + kk * 16 + lh];
        v8s b_l = *(const v8s*)&Bl[(1 * 66 + brow) * 72 + kk * 16 + lh];
        acc = __builtin_amdgcn_mfma_f32_32x32x16_bf16(a_h, b_h, acc, 0, 0, 0);
        acc = __builtin_amdgcn_mfma_f32_32x32x16_bf16(a_h, b_l, acc, 0, 0, 0);
        acc = __builtin_amdgcn_mfma_f32_32x32x16_bf16(a_l, b_h, acc, 0, 0, 0);
      }
    __syncthreads();
  }

  const int t_loc = w * 32 + (l & 31);
  const int hi4 = 4 * (l >> 5);
#pragma unroll
  for (int q4 = 0; q4 < 4; ++q4)
#pragma unroll
    for (int j = 0; j < 4; ++j) {
      int co = q4 * 8 + hi4 + j;
      if (co < 17) {
        float z = acc[q4 * 4 + j] + Bs[co];
        magS[t_loc][co] = z * z;
      }
    }
  __syncthreads();

  if (tid < 64) {
    int i = t0 + tid;
    float xv[32];
#pragma unroll
    for (int n = 0; n < 32; ++n) {
      int idx = i * 16 + n;
      xv[n] = (idx < 16384) ? noise[(size_t)b * 16384 + idx] : 0.f;
    }
    float Yr[17], Yi[17];
#pragma unroll
    for (int k = 0; k <= 16; ++k) {
      float xr = 0.f, xi = 0.f;
      int kk = 0;
#pragma unroll
      for (int n = 0; n < 32; ++n) {
        xr += xv[n] * ctS[kk];
        xi -= xv[n] * stS[kk];
        kk = (kk + k) & 31;
      }
      float m = magS[tid][k];
      Yr[k] = xr * m;
      Yi[k] = xi * m;
    }
    float* fo = filt + ((size_t)(b << 10) + i) * 32;
#pragma unroll
    for (int n = 0; n < 32; ++n) {
      float v = Yr[0] + ((n & 1) ? -Yr[16] : Yr[16]);
      int kk = n;
#pragma unroll
      for (int k = 1; k <= 15; ++k) {
        v += 2.f * (Yr[k] * ctS[kk] - Yi[k] * stS[kk]);
        kk = (kk + n) & 31;
      }
      fo[n] = v * (1.f / 32.f);
    }
  }
}

// -------------------------------------------------------------------------
// Oscillator bank (3-point lerp endpoints + f64 chunk base + f32 Kahan).
// -------------------------------------------------------------------------
static __device__ __forceinline__ int clamp64(int i) { return i < 0 ? 0 : (i > 63 ? 63 : i); }

__global__ void __launch_bounds__(256) osc_phase(
    const float* __restrict__ fsm, double* __restrict__ phaseBase)
{
  const int o = blockIdx.x, b = blockIdx.y;
  const float* frow = fsm + (size_t)(b * 128 + o) * 64;
  const int c = threadIdx.x;

  const float ic0 = ((float)(c * 64) - 127.5f) * (1.0f / 256.0f);
  const int ilo = (int)floorf(ic0);
  float f0 = frow[clamp64(ilo)], f1 = frow[clamp64(ilo + 1)], f2 = frow[clamp64(ilo + 2)];

  double local = 0.0;
#pragma unroll 8
  for (int j = 0; j < 64; ++j) {
    float ic = ic0 + (float)j * (1.0f / 256.0f);
    float fl = floorf(ic);
    float w  = ic - fl;
    bool hi = ((int)fl) > ilo;
    float fa = hi ? f1 : f0;
    float fb = hi ? f2 : f1;
    float f = fa * (1.f - w) + fb * w;
    f = fminf(fmaxf(f, 20.f), 11025.f);
    local += (double)f;
  }
  local *= (1.0 / 22050.0);

  __shared__ double ps[256];
  ps[c] = local;
  __syncthreads();
  for (int off = 1; off < 256; off <<= 1) {
    double v = (c >= off) ? ps[c - off] : 0.0;
    __syncthreads();
    ps[c] += v;
    __syncthreads();
  }
  phaseBase[(size_t)(b * 128 + o) * 256 + c] = ps[c] - local;
}

__global__ void __launch_bounds__(128) osc_sum(
    const float* __restrict__ fsm, const float* __restrict__ lsm,
    const double* __restrict__ phaseBase, const float* __restrict__ filt,
    float* __restrict__ out)
{
  const int c = blockIdx.x, b = blockIdx.y;
  const int tid = threadIdx.x;
  __shared__ float contrib[128][65];
  __shared__ float part[2][64];
  const int o = tid;
  const float* frow = fsm + (size_t)(b * 128 + o) * 64;
  const float* arow = lsm + (size_t)(b * 128 + o) * 64;

  double pb = phaseBase[(size_t)(b * 128 + o) * 256 + c];
  float fb0 = (float)(pb - floor(pb));

  const float ic0 = ((float)(c * 64) - 127.5f) * (1.0f / 256.0f);
  const int ilo = (int)floorf(ic0);
  float f0 = frow[clamp64(ilo)], f1 = frow[clamp64(ilo + 1)], f2 = frow[clamp64(ilo + 2)];
  float a0 = arow[clamp64(ilo)], a1 = arow[clamp64(ilo + 1)], a2 = arow[clamp64(ilo + 2)];

  float rel = 0.f, comp = 0.f;
#pragma unroll 8
  for (int j = 0; j < 64; ++j) {
    float ic = ic0 + (float)j * (1.0f / 256.0f);
    float fl = floorf(ic);
    float w  = ic - fl;
    bool hi = ((int)fl) > ilo;
    float fa = hi ? f1 : f0;
    float fb = hi ? f2 : f1;
    float f = fa * (1.f - w) + fb * w;
    f = fminf(fmaxf(f, 20.f), 11025.f);
    float y = f * (1.0f / 22050.0f) - comp;
    float t = rel + y;
    comp = (t - rel) - y;
    rel = t;
    float tot = fb0 + rel;
    float frac = tot - floorf(tot);
    float s = sinpif(2.f * frac);
    float aa = hi ? a1 : a0;
    float ab = hi ? a2 : a1;
    float am = aa * (1.f - w) + ab * w;
    contrib[o][j] = s * am;
  }
  __syncthreads();
  int half = tid >> 6, tl = tid & 63;
  float sum = 0.f;
  for (int oo = 0; oo < 64; ++oo) sum += contrib[half * 64 + oo][tl];
  part[half][tl] = sum;
  __syncthreads();
  if (tid < 64) {
    int t = c * 64 + tid;
    float v = part[0][tid] + part[1][tid];
    int i0 = t >> 4, r = t & 15;
    v += filt[((size_t)(b << 10) + i0) * 32 + r];
    if (i0 > 0) v += filt[((size_t)(b << 10) + i0 - 1) * 32 + 16 + r];
    out[(size_t)b * 16384 + t] = v;
  }
}

// -------------------------------------------------------------------------
extern "C" void kernel_launch(void* const* d_in, const int* in_sizes, int n_in,
                              void* d_out, int out_size, void* d_ws, size_t ws_size,
                              hipStream_t stream)
{
  (void)in_sizes; (void)n_in; (void)out_size;

  const float* x     = (const float*)d_in[0];
  const float* noise = (const float*)d_in[1];
  const float* mw0 = (const float*)d_in[2];  const float* mb0 = (const float*)d_in[3];
  const float* mw1 = (const float*)d_in[4];  const float* mb1 = (const float*)d_in[5];
  const float* mw2 = (const float*)d_in[6];  const float* mb2 = (const float*)d_in[7];
  const float* mw3 = (const float*)d_in[8];  const float* mb3 = (const float*)d_in[9];
  const float* fw  = (const float*)d_in[10]; const float* fb  = (const float*)d_in[11];
  const float* gw0 = (const float*)d_in[12]; const float* gb0 = (const float*)d_in[13];
  const float* gw1 = (const float*)d_in[14]; const float* gb1 = (const float*)d_in[15];
  const float* gw2 = (const float*)d_in[16]; const float* gb2 = (const float*)d_in[17];
  const float* gw3 = (const float*)d_in[18]; const float* gb3 = (const float*)d_in[19];
  const float* lw  = (const float*)d_in[20]; const float* lb  = (const float*)d_in[21];
  const float* nw0 = (const float*)d_in[22]; const float* nb0 = (const float*)d_in[23];
  const float* nw1 = (const float*)d_in[24]; const float* nb1 = (const float*)d_in[25];
  const float* nw2 = (const float*)d_in[26]; const float* nb2 = (const float*)d_in[27];
  const float* nw3 = (const float*)d_in[28]; const float* nb3 = (const float*)d_in[29];
  const float* nlw = (const float*)d_in[30]; const float* nlb = (const float*)d_in[31];

  char* W8 = (char*)d_ws;
  float* out = (float*)d_out;
  const int PS_X = 131072;   // xm3 plane stride (shorts)
  const int PS_H = 524288;   // m/g act plane stride (shorts)

  const bool bigws = (ws_size >= 144113664ull);

  if (bigws) {
    // ======== SERIAL schedule, fully DISJOINT layout (144.1 MB) ========
    // No aliasing -> fold runs inside the single prep launch.
    short* mP  = (short*)(W8 + 0);
    short* gP  = (short*)(W8 + 16515072);
    short* hm0 = (short*)(W8 + 33030144);
    short* hm1 = (short*)(W8 + 36175872);
    short* hg0 = (short*)(W8 + 39321600);
    short* hg1 = (short*)(W8 + 42467328);
    short* xm3 = (short*)(W8 + 45613056);
    float* fsm = (float*)(W8 + 46399488);
    float* lsm = (float*)(W8 + 46923776);
    short* Pnl = (short*)(W8 + 47448064);
    short* E1  = (short*)(W8 + 47644672);
    short* E2  = (short*)(W8 + 49741824);
    short* E3  = (short*)(W8 + 58130432);
    short* E4  = (short*)(W8 + 66519040);
    short* l1out = (short*)(W8 + 74907648);
    short* l2out = (short*)(W8 + 79101952);
    short* l3out = (short*)(W8 + 87490560);
    short* l4act = (short*)(W8 + 104267776);
    float* filt  = (float*)(W8 + 137822208);
    double* phaseBase = (double*)(W8 + 139919360);

    prep_all<<<1832, 256, 0, stream>>>(x, xm3,
        mw0, mw1, mw2, mw3, fw, gw0, gw1, gw2, gw3, lw, mP, gP,
        nw0, nw1, nw2, nw3, nlw, E1, E2, E3, E4, Pnl);

    conv_path<<<256, 256, 0, stream>>>(xm3, xm3, mP + 0, gP + 0, mb0, gb0,
        nullptr, nullptr, hm0, hg0, 128, 512, PS_X, PS_H, ACT_LRELU, ACT_LRELU);
    conv_path<<<256, 256, 0, stream>>>(hm0, hg0, mP + 589824, gP + 589824, mb1, gb1,
        nullptr, nullptr, hm1, hg1, 512, 512, PS_H, PS_H, ACT_LRELU, ACT_LRELU);
    conv_path<<<256, 256, 0, stream>>>(hm1, hg1, mP + 2949120, gP + 2949120, mb2, gb2,
        nullptr, nullptr, hm0, hg0, 512, 512, PS_H, PS_H, ACT_LRELU, ACT_LRELU);
    conv_path<<<256, 256, 0, stream>>>(hm0, hg0, mP + 5308416, gP + 5308416, mb3, gb3,
        nullptr, nullptr, hm1, hg1, 512, 512, PS_H, PS_H, ACT_LRELU, ACT_LRELU);
    conv_path<<<64, 256, 0, stream>>>(hm1, hg1, mP + 7667712, gP + 7667712, fb, lb,
        fsm, lsm, nullptr, nullptr, 512, 128, PS_H, 0, ACT_SIGMAP, ACT_SQUARE);

    conv_noise<1, 64, 128><<<256, 256, 0, stream>>>(xm3, E1, nb0, l1out, 64, PS_X, 1048576);
    conv_noise<2, 64, 512><<<256, 256, 0, stream>>>(l1out, E2, nb1, l2out, 128, 1048576, 2097152);
    conv_noise<2, 128, 512><<<256, 256, 0, stream>>>(l2out, E3, nb2, l3out, 256, 2097152, 4194304);
    conv_noise<2, 128, 512><<<512, 256, 0, stream>>>(l3out, E4, nb3, l4act, 512, 4194304, 8388608);

    conv_nl_filter<<<256, 128, 0, stream>>>(l4act, Pnl, nlb, noise, filt);
    osc_phase<<<dim3(128, 16), 256, 0, stream>>>(fsm, phaseBase);
    osc_sum<<<dim3(256, 16), 128, 0, stream>>>(fsm, lsm, phaseBase, filt, out);
  } else {
    // ======== SERIAL schedule, ALIASED round-12 layout (60.75 MB) ========
    short* mP  = (short*)(W8 + 0);
    short* gP  = (short*)(W8 + 16515072);
    short* hm0 = (short*)(W8 + 33030144);
    short* hm1 = (short*)(W8 + 36175872);
    short* hg0 = (short*)(W8 + 39321600);
    short* hg1 = (short*)(W8 + 42467328);
    short* xm3 = (short*)(W8 + 58720256);
    float* fsm = (float*)(W8 + 59506688);
    float* lsm = (float*)(W8 + 60030976);
    short* Pnl = (short*)(W8 + 60555264);

    short* E4  = (short*)(W8 + 0);
    short* E3  = (short*)(W8 + 33554432);
    short* E2  = (short*)(W8 + 41943040);
    short* E1  = (short*)(W8 + 50331648);
    short* l1out = (short*)(W8 + 52428800);
    short* l2out = (short*)(W8 + 25165824);
    short* l3out = (short*)(W8 + 8388608);
    short* l4act = (short*)(W8 + 25165824);

    float* filt = (float*)(W8 + 1114112);
    double* phaseBase = (double*)(W8 + 4194304);

    prep_all<<<1408, 256, 0, stream>>>(x, xm3,
        mw0, mw1, mw2, mw3, fw, gw0, gw1, gw2, gw3, lw, mP, gP,
        nw0, nw1, nw2, nw3, nlw, E1, E2, E3, E4, Pnl);

    conv_path<<<256, 256, 0, stream>>>(xm3, xm3, mP + 0, gP + 0, mb0, gb0,
        nullptr, nullptr, hm0, hg0, 128, 512, PS_X, PS_H, ACT_LRELU, ACT_LRELU);
    conv_path<<<256, 256, 0, stream>>>(hm0, hg0, mP + 589824, gP + 589824, mb1, gb1,
        nullptr, nullptr, hm1, hg1, 512, 512, PS_H, PS_H, ACT_LRELU, ACT_LRELU);
    conv_path<<<256, 256, 0, stream>>>(hm1, hg1, mP + 2949120, gP + 2949120, mb2, gb2,
        nullptr, nullptr, hm0, hg0, 512, 512, PS_H, PS_H, ACT_LRELU, ACT_LRELU);
    conv_path<<<256, 256, 0, stream>>>(hm0, hg0, mP + 5308416, gP + 5308416, mb3, gb3,
        nullptr, nullptr, hm1, hg1, 512, 512, PS_H, PS_H, ACT_LRELU, ACT_LRELU);
    conv_path<<<64, 256, 0, stream>>>(hm1, hg1, mP + 7667712, gP + 7667712, fb, lb,
        fsm, lsm, nullptr, nullptr, 512, 128, PS_H, 0, ACT_SIGMAP, ACT_SQUARE);

    fold_all<<<424, 256, 0, stream>>>(nw0, nw1, nw2, nw3, nlw, E1, E2, E3, E4, Pnl);
    conv_noise<1, 64, 128><<<256, 256, 0, stream>>>(xm3, E1, nb0, l1out, 64, PS_X, 1048576);
    conv_noise<2, 64, 512><<<256, 256, 0, stream>>>(l1out, E2, nb1, l2out, 128, 1048576, 2097152);
    conv_noise<2, 128, 512><<<256, 256, 0, stream>>>(l2out, E3, nb2, l3out, 256, 2097152, 4194304);
    conv_noise<2, 128, 512><<<512, 256, 0, stream>>>(l3out, E4, nb3, l4act, 512, 4194304, 8388608);

    conv_nl_filter<<<256, 128, 0, stream>>>(l4act, Pnl, nlb, noise, filt);
    osc_phase<<<dim3(128, 16), 256, 0, stream>>>(fsm, phaseBase);
    osc_sum<<<dim3(256, 16), 128, 0, stream>>>(fsm, lsm, phaseBase, filt, out);
  }
}